// Round 5
// baseline (130.528 us; speedup 1.0000x reference)
//
#include <hip/hip_runtime.h>
#include <math.h>

#define EDIM 256
#define LDIM 1024
#define HDIM 8
#define DDIM 32

typedef __attribute__((ext_vector_type(8))) short short8;
typedef __attribute__((ext_vector_type(4))) short short4v;
typedef __attribute__((ext_vector_type(4))) float f32x4;

__device__ inline unsigned short bf16h(float x) {
    unsigned u = __float_as_uint(x);
    return (unsigned short)((u + 0x7fff + ((u >> 16) & 1)) >> 16);   // RNE
}
__device__ inline float bf16tof(unsigned short h) {
    return __uint_as_float(((unsigned)h) << 16);
}

// ---------------------------------------------------------------------------
// convert_kernel: split fp32 arrays into (hi, lo) bf16 arrays, same layout.
// blockIdx.y selects the array; 8 elements per thread (two float4 -> short8).
// ---------------------------------------------------------------------------
__global__ __launch_bounds__(256) void convert_kernel(
    const float* __restrict__ Q, const float* __restrict__ K, const float* __restrict__ V,
    const float* __restrict__ Wq, const float* __restrict__ Wk, const float* __restrict__ Wv,
    const float* __restrict__ Wo,
    short* __restrict__ Qh, short* __restrict__ Ql, short* __restrict__ Kh, short* __restrict__ Kl,
    short* __restrict__ Vh, short* __restrict__ Vl, short* __restrict__ Wqh, short* __restrict__ Wql,
    short* __restrict__ Wkh, short* __restrict__ Wkl, short* __restrict__ Wvh, short* __restrict__ Wvl,
    short* __restrict__ Woh, short* __restrict__ Wol)
{
    const int z = blockIdx.y;
    const float* src; short* dh; short* dl; int cnt;
    switch (z) {
        case 0: src = Q;  dh = Qh;  dl = Ql;  cnt = LDIM*EDIM; break;
        case 1: src = K;  dh = Kh;  dl = Kl;  cnt = LDIM*EDIM; break;
        case 2: src = V;  dh = Vh;  dl = Vl;  cnt = LDIM*EDIM; break;
        case 3: src = Wq; dh = Wqh; dl = Wql; cnt = EDIM*EDIM; break;
        case 4: src = Wk; dh = Wkh; dl = Wkl; cnt = EDIM*EDIM; break;
        case 5: src = Wv; dh = Wvh; dl = Wvl; cnt = EDIM*EDIM; break;
        default: src = Wo; dh = Woh; dl = Wol; cnt = EDIM*EDIM; break;
    }
    const int idx = (blockIdx.x * 256 + threadIdx.x) * 8;
    if (idx >= cnt) return;
    float4 a = *(const float4*)(src + idx);
    float4 b = *(const float4*)(src + idx + 4);
    float v[8] = {a.x,a.y,a.z,a.w, b.x,b.y,b.z,b.w};
    short8 hi, lo;
    #pragma unroll
    for (int j = 0; j < 8; ++j) {
        unsigned short hh = bf16h(v[j]);
        hi[j] = (short)hh;
        lo[j] = (short)bf16h(v[j] - bf16tof(hh));
    }
    *(short8*)&dh[idx] = hi;
    *(short8*)&dl[idx] = lo;
}

// ---------------------------------------------------------------------------
// proj_kernel (MFMA): dst(H,L,D) = X(L,E) @ W(E,E)^T per blockIdx.z, computed
// with split-bf16 3-term MFMA. Fragments are DIRECT global 16B loads (row-major
// with K contiguous == frag layout): no LDS, no barriers. 64x64 per block,
// 4 waves, each wave a 16-row strip x 4 col-tiles. z==0 fuses coeff.
// ---------------------------------------------------------------------------
__global__ __launch_bounds__(256) void proj_kernel(
    const short* __restrict__ Qh, const short* __restrict__ Ql,
    const short* __restrict__ Kh, const short* __restrict__ Kl,
    const short* __restrict__ Vh, const short* __restrict__ Vl,
    const short* __restrict__ Wqh, const short* __restrict__ Wql,
    const short* __restrict__ Wkh, const short* __restrict__ Wkl,
    const short* __restrict__ Wvh, const short* __restrict__ Wvl,
    const float* __restrict__ Wr,
    float* __restrict__ qT, float* __restrict__ kT, float* __restrict__ vT,
    float* __restrict__ coeff)
{
    const int z = blockIdx.z;
    const short* __restrict__ Xh = (z == 0) ? Qh : (z == 1) ? Kh : Vh;
    const short* __restrict__ Xl = (z == 0) ? Ql : (z == 1) ? Kl : Vl;
    const short* __restrict__ Wh = (z == 0) ? Wqh : (z == 1) ? Wkh : Wvh;
    const short* __restrict__ Wl = (z == 0) ? Wql : (z == 1) ? Wkl : Wvl;
    float* __restrict__ dst      = (z == 0) ? qT : (z == 1) ? kT : vT;

    const int n0 = blockIdx.x * 64;
    const int o0 = blockIdx.y * 64;
    const int wave = threadIdx.x >> 6;
    const int lane = threadIdx.x & 63;
    const int n16  = lane & 15;
    const int quad = lane >> 4;

    const int mrow = n0 + wave*16 + n16;     // A row (sequence index)

    f32x4 acc[4];
    #pragma unroll
    for (int t4 = 0; t4 < 4; ++t4) acc[t4] = (f32x4){0.f,0.f,0.f,0.f};

    #pragma unroll 2
    for (int kb = 0; kb < EDIM; kb += 32) {
        short8 ah = *(const short8*)&Xh[mrow*EDIM + kb + quad*8];
        short8 al = *(const short8*)&Xl[mrow*EDIM + kb + quad*8];
        #pragma unroll
        for (int t4 = 0; t4 < 4; ++t4) {
            const int orow = o0 + 16*t4 + n16;   // B col = W row
            short8 bh = *(const short8*)&Wh[orow*EDIM + kb + quad*8];
            short8 bl = *(const short8*)&Wl[orow*EDIM + kb + quad*8];
            acc[t4] = __builtin_amdgcn_mfma_f32_16x16x32_bf16(al, bh, acc[t4], 0, 0, 0);
            acc[t4] = __builtin_amdgcn_mfma_f32_16x16x32_bf16(ah, bl, acc[t4], 0, 0, 0);
            acc[t4] = __builtin_amdgcn_mfma_f32_16x16x32_bf16(ah, bh, acc[t4], 0, 0, 0);
        }
    }

    // C/D layout: row = quad*4+i, col = lane&15 (per 16-col tile)
    #pragma unroll
    for (int t4 = 0; t4 < 4; ++t4) {
        const int o = o0 + 16*t4 + n16;
        const int h = o >> 5, d = o & 31;
        #pragma unroll
        for (int i = 0; i < 4; ++i) {
            const int r = n0 + wave*16 + quad*4 + i;
            dst[h*(LDIM*DDIM) + r*DDIM + d] = acc[t4][i];
        }
    }

    if (z == 0) {
        // coeff[h][r] = sum_{d} q[r][h*32+d] * Wr[h*32+d]
        // head h0 = cols of t4 0,1 ; head h1 = cols of t4 2,3
        float wr[4];
        #pragma unroll
        for (int t4 = 0; t4 < 4; ++t4) wr[t4] = Wr[o0 + 16*t4 + n16];
        const int h0 = o0 >> 5;
        #pragma unroll
        for (int i = 0; i < 4; ++i) {
            float c0 = acc[0][i]*wr[0] + acc[1][i]*wr[1];
            float c1 = acc[2][i]*wr[2] + acc[3][i]*wr[3];
            #pragma unroll
            for (int off = 1; off < 16; off <<= 1) {
                c0 += __shfl_xor(c0, off, 64);
                c1 += __shfl_xor(c1, off, 64);
            }
            if (n16 == 0) {
                const int r = n0 + wave*16 + quad*4 + i;
                coeff[h0*LDIM + r]     = c0;
                coeff[(h0+1)*LDIM + r] = c1;
            }
        }
    }
}

// ---------------------------------------------------------------------------
// attn_kernel: flash attention, QK^T on MFMA (split-bf16 hi/lo), softmax in
// C/D layout, PV on VALU via transposed P in LDS. Unchanged from round 4.
// ---------------------------------------------------------------------------
__global__ __launch_bounds__(256, 4) void attn_kernel(
    const float* __restrict__ qT, const float* __restrict__ kT, const float* __restrict__ vT,
    const float* __restrict__ coeff, const float* __restrict__ pos,
    float* __restrict__ Op, float* __restrict__ Mp, float* __restrict__ Lp, int nkt)
{
    const int h   = blockIdx.y;
    const int q0  = blockIdx.x * 64;
    const int p   = blockIdx.z;
    const int kt0 = p * nkt * 64;
    const int tid  = threadIdx.x;
    const int wave = tid >> 6;
    const int lane = tid & 63;
    const int n    = lane & 15;
    const int quad = lane >> 4;
    const int qs0  = wave * 16;

    __shared__ __align__(16) short khi[4*64*8];
    __shared__ __align__(16) short klo[4*64*8];
    __shared__ float vs[64][36];
    __shared__ float ps_t[64][68];
    __shared__ float alph[64];
    __shared__ float pk[64];

    short8 qhi, qlo;
    {
        const float* qp = qT + (h*LDIM + q0 + qs0 + n) * DDIM + quad*8;
        float4 qa = *(const float4*)qp;
        float4 qb = *(const float4*)(qp + 4);
        float v[8] = {qa.x,qa.y,qa.z,qa.w, qb.x,qb.y,qb.z,qb.w};
        #pragma unroll
        for (int j = 0; j < 8; ++j) {
            unsigned short hh = bf16h(v[j]);
            qhi[j] = (short)hh;
            qlo[j] = (short)bf16h(v[j] - bf16tof(hh));
        }
    }

    float pq[4], cq[4];
    #pragma unroll
    for (int i = 0; i < 4; ++i) {
        const int r = q0 + qs0 + 4*quad + i;
        pq[i] = pos[r];
        cq[i] = coeff[h*LDIM + r] * 0.0625f;
    }

    float m[4], l[4];
    #pragma unroll
    for (int i = 0; i < 4; ++i) { m[i] = -INFINITY; l[i] = 0.f; }

    const int pr0 = (tid >> 4) * 4;
    const int dg2 = (tid & 15) * 2;
    float o[4][2];
    #pragma unroll
    for (int i = 0; i < 4; ++i) { o[i][0] = 0.f; o[i][1] = 0.f; }

    const int cS = tid >> 2;
    const int dq = tid & 3;
    const int lane2 = (cS & 15) | (dq << 4);
    const int gS = cS >> 4;

    float4 k0c, k1c, v0c, v1c; float pkc = 0.f;
    {
        const float* kp = kT + (h*LDIM + kt0 + cS) * DDIM + dq*8;
        k0c = *(const float4*)kp; k1c = *(const float4*)(kp + 4);
        const float* vp = vT + (h*LDIM + kt0 + cS) * DDIM + dq*8;
        v0c = *(const float4*)vp; v1c = *(const float4*)(vp + 4);
        if (tid < 64) pkc = pos[kt0 + tid];
    }

    for (int t = 0; t < nkt; ++t) {
        __syncthreads();   // (A) prev consumers done

        {
            float kv[8] = {k0c.x,k0c.y,k0c.z,k0c.w, k1c.x,k1c.y,k1c.z,k1c.w};
            short8 hi8, lo8;
            #pragma unroll
            for (int j = 0; j < 8; ++j) {
                unsigned short hh = bf16h(kv[j]);
                hi8[j] = (short)hh;
                lo8[j] = (short)bf16h(kv[j] - bf16tof(hh));
            }
            *((short8*)&khi[(gS*64 + lane2)*8]) = hi8;
            *((short8*)&klo[(gS*64 + lane2)*8]) = lo8;
            *(float4*)&vs[cS][dq*8]     = v0c;
            *(float4*)&vs[cS][dq*8 + 4] = v1c;
            if (tid < 64) pk[tid] = pkc;
        }

        float4 k0n, k1n, v0n, v1n; float pkn = 0.f;
        if (t + 1 < nkt) {
            const int kt = kt0 + (t+1) * 64;
            const float* kp = kT + (h*LDIM + kt + cS) * DDIM + dq*8;
            k0n = *(const float4*)kp; k1n = *(const float4*)(kp + 4);
            const float* vp = vT + (h*LDIM + kt + cS) * DDIM + dq*8;
            v0n = *(const float4*)vp; v1n = *(const float4*)(vp + 4);
            if (tid < 64) pkn = pos[kt + tid];
        }
        __syncthreads();   // (B) staging visible

        f32x4 Sf[4];
        #pragma unroll
        for (int t4 = 0; t4 < 4; ++t4) {
            short8 bhi = *((const short8*)&khi[(t4*64 + lane)*8]);
            short8 blo = *((const short8*)&klo[(t4*64 + lane)*8]);
            f32x4 acc = {0.f, 0.f, 0.f, 0.f};
            acc = __builtin_amdgcn_mfma_f32_16x16x32_bf16(qlo, bhi, acc, 0, 0, 0);
            acc = __builtin_amdgcn_mfma_f32_16x16x32_bf16(qhi, blo, acc, 0, 0, 0);
            acc = __builtin_amdgcn_mfma_f32_16x16x32_bf16(qhi, bhi, acc, 0, 0, 0);
            Sf[t4] = acc;
        }

        float ev[4][4];
        float rmax[4] = {-INFINITY, -INFINITY, -INFINITY, -INFINITY};
        #pragma unroll
        for (int t4 = 0; t4 < 4; ++t4) {
            const float pkt = pk[16*t4 + n];
            #pragma unroll
            for (int i = 0; i < 4; ++i) {
                float s = fmaf(Sf[t4][i], 0.0625f, cq[i] * __logf(fabsf(pq[i] - pkt) + 1.f));
                ev[t4][i] = s;
                rmax[i] = fmaxf(rmax[i], s);
            }
        }
        #pragma unroll
        for (int off = 1; off < 16; off <<= 1)
            #pragma unroll
            for (int i = 0; i < 4; ++i)
                rmax[i] = fmaxf(rmax[i], __shfl_xor(rmax[i], off, 64));

        float al[4], rsum[4];
        #pragma unroll
        for (int i = 0; i < 4; ++i) {
            const float mn = fmaxf(m[i], rmax[i]);
            al[i] = __expf(m[i] - mn);
            m[i] = mn;
            rsum[i] = 0.f;
        }
        #pragma unroll
        for (int t4 = 0; t4 < 4; ++t4)
            #pragma unroll
            for (int i = 0; i < 4; ++i) {
                float e = __expf(ev[t4][i] - m[i]);
                ev[t4][i] = e;
                rsum[i] += e;
            }
        #pragma unroll
        for (int off = 1; off < 16; off <<= 1)
            #pragma unroll
            for (int i = 0; i < 4; ++i)
                rsum[i] += __shfl_xor(rsum[i], off, 64);
        #pragma unroll
        for (int i = 0; i < 4; ++i) l[i] = l[i]*al[i] + rsum[i];

        if (n == 0) {
            #pragma unroll
            for (int i = 0; i < 4; ++i) alph[qs0 + 4*quad + i] = al[i];
        }
        #pragma unroll
        for (int t4 = 0; t4 < 4; ++t4) {
            float4 w; w.x = ev[t4][0]; w.y = ev[t4][1]; w.z = ev[t4][2]; w.w = ev[t4][3];
            *(float4*)&ps_t[16*t4 + n][qs0 + 4*quad] = w;
        }
        __syncthreads();   // (C) ps_t/alph visible

        {
            float4 a4 = *(const float4*)&alph[pr0];
            o[0][0]*=a4.x; o[0][1]*=a4.x; o[1][0]*=a4.y; o[1][1]*=a4.y;
            o[2][0]*=a4.z; o[2][1]*=a4.z; o[3][0]*=a4.w; o[3][1]*=a4.w;
        }
        #pragma unroll 4
        for (int c = 0; c < 64; ++c) {
            float4 p4 = *(const float4*)&ps_t[c][pr0];
            float2 v2 = *(const float2*)&vs[c][dg2];
            o[0][0] += p4.x*v2.x; o[0][1] += p4.x*v2.y;
            o[1][0] += p4.y*v2.x; o[1][1] += p4.y*v2.y;
            o[2][0] += p4.z*v2.x; o[2][1] += p4.z*v2.y;
            o[3][0] += p4.w*v2.x; o[3][1] += p4.w*v2.y;
        }

        k0c = k0n; k1c = k1n; v0c = v0n; v1c = v1n; pkc = pkn;
    }

    const int ph = p * HDIM + h;
    #pragma unroll
    for (int i = 0; i < 4; ++i) {
        float2 w; w.x = o[i][0]; w.y = o[i][1];
        *(float2*)(Op + ((size_t)ph*LDIM + q0 + pr0 + i)*DDIM + dg2) = w;
    }
    if (n == 0) {
        #pragma unroll
        for (int i = 0; i < 4; ++i) {
            const int r = q0 + qs0 + 4*quad + i;
            Mp[ph*LDIM + r] = m[i];
            Lp[ph*LDIM + r] = l[i];
        }
    }
}

// ---------------------------------------------------------------------------
// combine_kernel: A(L,E) = normalized combine of P attention partials, output
// directly as split-bf16 (hi, lo) for the MFMA output projection.
// ---------------------------------------------------------------------------
__global__ __launch_bounds__(256) void combine_kernel(
    const float* __restrict__ Op, const float* __restrict__ Mp, const float* __restrict__ Lp,
    int P, short* __restrict__ Ah, short* __restrict__ Al)
{
    const int idx = blockIdx.x * 256 + threadIdx.x;   // 0..65535
    const int n  = idx >> 6;
    const int e4 = (idx & 63) * 4;
    const int h  = e4 >> 5;
    const int d  = e4 & 31;

    float mv[8], lv[8];
    float mx = -INFINITY;
    #pragma unroll
    for (int p = 0; p < 8; ++p) if (p < P) {
        mv[p] = Mp[(p*HDIM + h)*LDIM + n];
        lv[p] = Lp[(p*HDIM + h)*LDIM + n];
        mx = fmaxf(mx, mv[p]);
    }
    float s = 0.f;
    #pragma unroll
    for (int p = 0; p < 8; ++p) if (p < P) {
        float a = __expf(mv[p] - mx);
        mv[p] = a;
        s += a * lv[p];
    }
    const float inv = 1.f / s;

    float x[4] = {0.f, 0.f, 0.f, 0.f};
    #pragma unroll
    for (int p = 0; p < 8; ++p) if (p < P) {
        const float sp = mv[p] * inv;
        float4 xp = *(const float4*)(Op + ((size_t)(p*HDIM + h)*LDIM + n)*DDIM + d);
        x[0] += sp*xp.x; x[1] += sp*xp.y; x[2] += sp*xp.z; x[3] += sp*xp.w;
    }
    short4v hi, lo;
    #pragma unroll
    for (int j = 0; j < 4; ++j) {
        unsigned short hh = bf16h(x[j]);
        hi[j] = (short)hh;
        lo[j] = (short)bf16h(x[j] - bf16tof(hh));
    }
    *(short4v*)&Ah[n*EDIM + e4] = hi;
    *(short4v*)&Al[n*EDIM + e4] = lo;
}

// ---------------------------------------------------------------------------
// outproj_kernel (MFMA): out(L,E) = A(L,E) @ Wo(E,E)^T + bo, split-bf16
// 3-term MFMA with direct global fragment loads. 64x64 per block, grid (16,4).
// ---------------------------------------------------------------------------
__global__ __launch_bounds__(256) void outproj_kernel(
    const short* __restrict__ Ah, const short* __restrict__ Al,
    const short* __restrict__ Woh, const short* __restrict__ Wol,
    const float* __restrict__ bo, float* __restrict__ out)
{
    const int n0 = blockIdx.x * 64;
    const int o0 = blockIdx.y * 64;
    const int wave = threadIdx.x >> 6;
    const int lane = threadIdx.x & 63;
    const int n16  = lane & 15;
    const int quad = lane >> 4;

    const int mrow = n0 + wave*16 + n16;

    f32x4 acc[4];
    #pragma unroll
    for (int t4 = 0; t4 < 4; ++t4) acc[t4] = (f32x4){0.f,0.f,0.f,0.f};

    #pragma unroll 2
    for (int kb = 0; kb < EDIM; kb += 32) {
        short8 ah = *(const short8*)&Ah[mrow*EDIM + kb + quad*8];
        short8 al = *(const short8*)&Al[mrow*EDIM + kb + quad*8];
        #pragma unroll
        for (int t4 = 0; t4 < 4; ++t4) {
            const int orow = o0 + 16*t4 + n16;
            short8 bh = *(const short8*)&Woh[orow*EDIM + kb + quad*8];
            short8 bl = *(const short8*)&Wol[orow*EDIM + kb + quad*8];
            acc[t4] = __builtin_amdgcn_mfma_f32_16x16x32_bf16(al, bh, acc[t4], 0, 0, 0);
            acc[t4] = __builtin_amdgcn_mfma_f32_16x16x32_bf16(ah, bl, acc[t4], 0, 0, 0);
            acc[t4] = __builtin_amdgcn_mfma_f32_16x16x32_bf16(ah, bh, acc[t4], 0, 0, 0);
        }
    }

    #pragma unroll
    for (int t4 = 0; t4 < 4; ++t4) {
        const int o = o0 + 16*t4 + n16;
        const float b = bo[o];
        #pragma unroll
        for (int i = 0; i < 4; ++i) {
            const int r = n0 + wave*16 + quad*4 + i;
            out[r*EDIM + o] = acc[t4][i] + b;
        }
    }
}

// ---------------------------------------------------------------------------
extern "C" void kernel_launch(void* const* d_in, const int* in_sizes, int n_in,
                              void* d_out, int out_size, void* d_ws, size_t ws_size,
                              hipStream_t stream) {
    const float* V   = (const float*)d_in[0];
    const float* K   = (const float*)d_in[1];
    const float* Q   = (const float*)d_in[2];
    const float* pos = (const float*)d_in[3];
    const float* Wq  = (const float*)d_in[4];
    const float* Wk  = (const float*)d_in[5];
    const float* Wv  = (const float*)d_in[6];
    const float* Wr  = (const float*)d_in[7];
    const float* Wo  = (const float*)d_in[8];
    const float* bo  = (const float*)d_in[9];
    float* out = (float*)d_out;
    float* ws  = (float*)d_ws;

    // ---- workspace layout (in float units) ----
    // split-bf16 buffers: X arrays 262144 shorts (=131072 floats) each,
    // W arrays 65536 shorts (=32768 floats) each.
    float* base = ws;
    short* Qh  = (short*)(base);            short* Ql  = (short*)(base + 131072);
    short* Kh  = (short*)(base + 262144);   short* Kl  = (short*)(base + 393216);
    short* Vh  = (short*)(base + 524288);   short* Vl  = (short*)(base + 655360);
    short* Wqh = (short*)(base + 786432);   short* Wql = (short*)(base + 819200);
    short* Wkh = (short*)(base + 851968);   short* Wkl = (short*)(base + 884736);
    short* Wvh = (short*)(base + 917504);   short* Wvl = (short*)(base + 950272);
    short* Woh = (short*)(base + 983040);   short* Wol = (short*)(base + 1015808);
    float* qT    = base + 1048576;
    float* kT    = base + 1310720;
    float* vT    = base + 1572864;
    float* coeff = base + 1835008;
    short* Ah    = (short*)(base + 1843200);
    short* Al    = (short*)(base + 1974272);
    float* Op    = base + 2105344;

    auto need = [](int P) -> size_t {
        return (size_t)(2105344 + P*278528) * 4;
    };
    int P = 2;
    if (ws_size >= need(8)) P = 8;
    else if (ws_size >= need(4)) P = 4;

    float* Mp = Op + (size_t)P * 262144;
    float* Lp = Mp + (size_t)P * 8192;

    convert_kernel<<<dim3(128, 7),   256, 0, stream>>>(Q, K, V, Wq, Wk, Wv, Wo,
        Qh, Ql, Kh, Kl, Vh, Vl, Wqh, Wql, Wkh, Wkl, Wvh, Wvl, Woh, Wol);
    proj_kernel   <<<dim3(16, 4, 3), 256, 0, stream>>>(Qh, Ql, Kh, Kl, Vh, Vl,
        Wqh, Wql, Wkh, Wkl, Wvh, Wvl, Wr, qT, kT, vT, coeff);
    attn_kernel   <<<dim3(16, 8, P), 256, 0, stream>>>(qT, kT, vT, coeff, pos, Op, Mp, Lp, 16 / P);
    combine_kernel<<<dim3(256),      256, 0, stream>>>(Op, Mp, Lp, P, Ah, Al);
    outproj_kernel<<<dim3(16, 4),    256, 0, stream>>>(Ah, Al, Woh, Wol, bo, out);
}